// Round 4
// baseline (279.463 us; speedup 1.0000x reference)
//
#include <hip/hip_runtime.h>

// ---------------------------------------------------------------------------
// TransVLAD fused pipeline for MI355X (gfx950)
// Shapes: N=32, C=512, H=W=32 (P=1024), E=1024, G=8, D=128, K=64
// out: [N, K*D] fp32 (262144)
//
// R4: K4 was grid- AND LDS-limited to 2 blocks/CU (19.5% occ, no pipe >40%).
//  - K4: qh-split P into quarters (grid 1024), xglds staged in 64-px halves
//    (LDS 63->47KB => 3 blocks/CU), atomicAdd into agg[n][g][k][d] (8MB,
//    memset-async zeroed). Workspace stays at R3-proven 120,061,952 B.
//  - K1: single x read (bf16 LDS cache), 160->96MB traffic.
//  - K3a: ushort4/float4 vectorized.
//  - k0a merged into k0.
// ---------------------------------------------------------------------------

#define N_  32
#define C_  512
#define P_  1024
#define E_  1024
#define G_  8
#define D_  128
#define K_  64

typedef __attribute__((ext_vector_type(8))) short bf16x8;
typedef __attribute__((ext_vector_type(4))) float f32x4;

__device__ __forceinline__ unsigned short f2b(float f) {
    union { float f; unsigned u; } v; v.f = f;
    unsigned r = (v.u + 0x7FFFu + ((v.u >> 16) & 1u)) >> 16;
    return (unsigned short)r;
}
__device__ __forceinline__ float b2f(unsigned short h) {
    union { unsigned u; float f; } v; v.u = ((unsigned)h) << 16;
    return v.f;
}

// async global->LDS 16B copy: LDS dest must be wave-uniform base + lane*16
__device__ __forceinline__ void gl_lds16(const void* g, void* l) {
    __builtin_amdgcn_global_load_lds(
        (const __attribute__((address_space(1))) void*)g,
        (__attribute__((address_space(3))) void*)l, 16, 0, 0);
}

// ---------------------------------------------------------------------------
// K0: convert W1 -> bf16 AND build V[g][k][c] = sum_d Wc[k][d]*W1[g*128+d][c]
// grid 1024: bid = ((g*64)+k)*2 + ch ; thread c = ch*256 + t
__global__ __launch_bounds__(256) void k0_prep(const float* __restrict__ W1,
                                               const float* __restrict__ Wc,
                                               unsigned short* __restrict__ W1b,
                                               unsigned short* __restrict__ Vb) {
    int bid = blockIdx.x;
    int t = threadIdx.x;
    // part 1: W1 -> bf16 (1024 blocks * 512 elems = 524288 exactly)
    int i0 = bid * 512 + t;
    W1b[i0]       = f2b(W1[i0]);
    W1b[i0 + 256] = f2b(W1[i0 + 256]);
    // part 2: Vb
    int ch = bid & 1, k = (bid >> 1) & 63, g = bid >> 7;
    int c = ch * 256 + t;
    float acc = 0.f;
    #pragma unroll 8
    for (int d = 0; d < 128; ++d) {
        acc += Wc[k * 128 + d] * W1[(g * 128 + d) * C_ + c];
    }
    Vb[(g * 64 + k) * C_ + c] = f2b(acc);
}

// ---------------------------------------------------------------------------
// K1: per-pixel L2 norm over C, write x_hat transposed: xhat_t [N][P][C] bf16
// grid (16,32): p0 = bx*64, n = by. Single global read of x via bf16 LDS cache.
__global__ __launch_bounds__(256) void k1_norm_transpose(const float* __restrict__ x,
                                                         unsigned short* __restrict__ xhat_t) {
    __shared__ short xc[128 * 256];   // [i][t]: c = (t>>6)*128+i, p = p0+(t&63)
    __shared__ float red[256];
    __shared__ float rn[64];
    int n = blockIdx.y;
    int p0 = blockIdx.x * 64;
    int t = threadIdx.x;
    int ps = t & 63, cs = t >> 6;

    float ss = 0.f;
    for (int i = 0; i < 128; ++i) {
        float v = x[((size_t)(n * C_ + cs * 128 + i)) * P_ + p0 + ps];
        ss += v * v;
        xc[i * 256 + t] = (short)f2b(v);     // lanes consecutive -> conflict-free
    }
    red[t] = ss;
    __syncthreads();
    if (t < 64) {
        float s = red[t] + red[64 + t] + red[128 + t] + red[192 + t];
        rn[t] = 1.0f / fmaxf(sqrtf(s), 1e-12f);
    }
    __syncthreads();

    float r = rn[ps];
    size_t base = ((size_t)(n * P_ + p0 + ps)) * C_ + cs * 128;
    #pragma unroll
    for (int jj = 0; jj < 16; ++jj) {
        bf16x8 o;
        #pragma unroll
        for (int j = 0; j < 8; ++j)
            o[j] = (short)f2b(b2f((unsigned short)xc[(jj * 8 + j) * 256 + t]) * r);
        *(bf16x8*)&xhat_t[base + jj * 8] = o;   // 16B/lane, per-thread rows; L2 merges
    }
}

// ---------------------------------------------------------------------------
// K2: xe[n][e][p] = sum_c W1b[e][c] * xhat_t[n][p][c]   (bf16 MFMA GEMM, NT)
// grid (64, 32): e0 = (bx>>3)*128, p0 = (bx&7)*128, n = by. 256 thr = 4 waves.
__global__ __launch_bounds__(256) void k2_gemm_xe(const unsigned short* __restrict__ W1b,
                                                  const unsigned short* __restrict__ xhat_t,
                                                  unsigned short* __restrict__ xe) {
    __shared__ __align__(16) short As[128 * 32];
    __shared__ __align__(16) short Bs[128 * 32];
    int n = blockIdx.y;
    int e0 = (blockIdx.x >> 3) * 128;
    int p0 = (blockIdx.x & 7) * 128;
    int t = threadIdx.x;
    int w = t >> 6, l = t & 63, q = l >> 4, l15 = l & 15;
    int wr = w >> 1, wc = w & 1;

    f32x4 acc[4][4];
    #pragma unroll
    for (int mi = 0; mi < 4; ++mi)
        #pragma unroll
        for (int ni = 0; ni < 4; ++ni)
            acc[mi][ni] = (f32x4){0.f, 0.f, 0.f, 0.f};

    for (int ks = 0; ks < 16; ++ks) {
        int k0 = ks * 32;
        #pragma unroll
        for (int i = 0; i < 2; ++i) {
            int ch = i * 256 + t;
            int row = ch >> 2, col = (ch & 3) * 8;
            gl_lds16(&W1b[(e0 + row) * C_ + k0 + col], &As[ch * 8]);
        }
        #pragma unroll
        for (int i = 0; i < 2; ++i) {
            int ch = i * 256 + t;
            int row = ch >> 2, col = (ch & 3) * 8;
            gl_lds16(&xhat_t[((size_t)(n * P_ + p0 + row)) * C_ + k0 + col], &Bs[ch * 8]);
        }
        __syncthreads();

        bf16x8 af[4], bf[4];
        #pragma unroll
        for (int mi = 0; mi < 4; ++mi)
            af[mi] = *(const bf16x8*)&As[(wr * 64 + mi * 16 + l15) * 32 + q * 8];
        #pragma unroll
        for (int ni = 0; ni < 4; ++ni)
            bf[ni] = *(const bf16x8*)&Bs[(wc * 64 + ni * 16 + l15) * 32 + q * 8];
        #pragma unroll
        for (int mi = 0; mi < 4; ++mi)
            #pragma unroll
            for (int ni = 0; ni < 4; ++ni)
                acc[mi][ni] = __builtin_amdgcn_mfma_f32_16x16x32_bf16(af[mi], bf[ni], acc[mi][ni], 0, 0, 0);
        __syncthreads();
    }

    #pragma unroll
    for (int mi = 0; mi < 4; ++mi) {
        #pragma unroll
        for (int ni = 0; ni < 4; ++ni) {
            #pragma unroll
            for (int r = 0; r < 4; ++r) {
                int e = e0 + wr * 64 + mi * 16 + q * 4 + r;
                int p = p0 + wc * 64 + ni * 16 + l15;
                xe[((size_t)(n * E_ + e)) * P_ + p] = f2b(acc[mi][ni][r]);
            }
        }
    }
}

// ---------------------------------------------------------------------------
// K3a: att partials over 64-wide e-chunks, 4 pixels/thread (ushort4/float4).
// grid (16, 32): ec = bx (0..15); n = by. p = t*4 .. t*4+3.
__global__ __launch_bounds__(256) void k3a_att_part(const unsigned short* __restrict__ xe,
                                                    const float* __restrict__ W2,
                                                    float* __restrict__ att_part) {
    int n = blockIdx.y;
    int ec = blockIdx.x;
    int t = threadIdx.x;
    int e0 = ec * 64;
    f32x4 acc[8];
    #pragma unroll
    for (int g = 0; g < 8; ++g) acc[g] = (f32x4){0.f, 0.f, 0.f, 0.f};
    #pragma unroll 4
    for (int i = 0; i < 64; ++i) {
        int e = e0 + i;
        ushort4 v4 = *(const ushort4*)&xe[((size_t)(n * E_ + e)) * P_ + t * 4];
        f32x4 vf = {b2f(v4.x), b2f(v4.y), b2f(v4.z), b2f(v4.w)};
        #pragma unroll
        for (int g = 0; g < 8; ++g)
            acc[g] += vf * W2[g * E_ + e];         // wave-uniform s_load
    }
    #pragma unroll
    for (int g = 0; g < 8; ++g)
        *(f32x4*)&att_part[(((size_t)(n * 16 + ec)) * 8 + g) * P_ + t * 4] = acc[g];
}

// K3b: att_s[n][g][p] = sigmoid( sum_ec att_part[n][ec][g][p] )
__global__ __launch_bounds__(256) void k3b_att_reduce(const float* __restrict__ att_part,
                                                      float* __restrict__ att_s) {
    int idx = blockIdx.x * 256 + threadIdx.x;   // grid 1024 -> 262144 exactly
    int p = idx & 1023;
    int g = (idx >> 10) & 7;
    int n = idx >> 13;
    float s = 0.f;
    #pragma unroll
    for (int ec = 0; ec < 16; ++ec)
        s += att_part[(((size_t)(n * 16 + ec)) * 8 + g) * P_ + p];
    att_s[idx] = 1.0f / (1.0f + __expf(-s));
}

// ---------------------------------------------------------------------------
// K4: fused assignment -> softmax -> gate -> aggregation per (n, g, qh)
// grid (32, 32): g = bx&7, qh = bx>>3 (P quarter), n = by. 256 thr = 4 waves.
// Aggregates via atomicAdd into agg[n][g][k][d] / wsum[n][g][k] (pre-zeroed).
__global__ __launch_bounds__(256) void k4_assign_agg(const unsigned short* __restrict__ Vb,
                                                     const unsigned short* __restrict__ xhat_t,
                                                     const unsigned short* __restrict__ xe,
                                                     const float* __restrict__ att_s,
                                                     float* __restrict__ agg,
                                                     float* __restrict__ wsum) {
    __shared__ __align__(16) short As2[64 * 32];      // Vb tile      (4 KB)
    __shared__ __align__(16) short Bs2[128 * 32];     // xhat tile    (8 KB)
    __shared__ __align__(16) short wlds[64 * 136];    // w, k-major   (17 KB)
    __shared__ __align__(16) short xglds[128 * 72];   // xg 64-px half(18 KB)

    int g = blockIdx.x & 7, qh = blockIdx.x >> 3, n = blockIdx.y;
    int t = threadIdx.x;
    int w = t >> 6, l = t & 63, q = l >> 4, l15 = l & 15;

    f32x4 acc_a[4][2];
    #pragma unroll
    for (int mi = 0; mi < 4; ++mi)
        #pragma unroll
        for (int ni = 0; ni < 2; ++ni)
            acc_a[mi][ni] = (f32x4){0.f, 0.f, 0.f, 0.f};
    float wsp[16];
    #pragma unroll
    for (int j = 0; j < 16; ++j) wsp[j] = 0.f;

    for (int cc = 0; cc < 2; ++cc) {
        int p0c = qh * 256 + cc * 128;

        // ---- Phase S: S = Vb[g] (64xC) * xhat^T (Cx128) ----
        f32x4 acc_s[4][2];
        #pragma unroll
        for (int mi = 0; mi < 4; ++mi)
            #pragma unroll
            for (int ni = 0; ni < 2; ++ni)
                acc_s[mi][ni] = (f32x4){0.f, 0.f, 0.f, 0.f};

        for (int ks = 0; ks < 16; ++ks) {
            int k0 = ks * 32;
            {   // As2: 64x32, 1 chunk/thread
                int row = t >> 2, col = (t & 3) * 8;
                gl_lds16(&Vb[(g * 64 + row) * C_ + k0 + col], &As2[t * 8]);
            }
            #pragma unroll
            for (int i = 0; i < 2; ++i) {   // Bs2: 128x32
                int ch = i * 256 + t;
                int row = ch >> 2, col = (ch & 3) * 8;
                gl_lds16(&xhat_t[((size_t)(n * P_ + p0c + row)) * C_ + k0 + col], &Bs2[ch * 8]);
            }
            __syncthreads();
            bf16x8 af[4], bf2[2];
            #pragma unroll
            for (int mi = 0; mi < 4; ++mi)
                af[mi] = *(const bf16x8*)&As2[(mi * 16 + l15) * 32 + q * 8];
            #pragma unroll
            for (int ni = 0; ni < 2; ++ni)
                bf2[ni] = *(const bf16x8*)&Bs2[(w * 32 + ni * 16 + l15) * 32 + q * 8];
            #pragma unroll
            for (int mi = 0; mi < 4; ++mi)
                #pragma unroll
                for (int ni = 0; ni < 2; ++ni)
                    acc_s[mi][ni] = __builtin_amdgcn_mfma_f32_16x16x32_bf16(af[mi], bf2[ni], acc_s[mi][ni], 0, 0, 0);
            __syncthreads();
        }

        // ---- softmax over k + gate ----
        #pragma unroll
        for (int ni = 0; ni < 2; ++ni) {
            float m = -1e30f;
            #pragma unroll
            for (int mi = 0; mi < 4; ++mi)
                #pragma unroll
                for (int r = 0; r < 4; ++r)
                    m = fmaxf(m, acc_s[mi][ni][r]);
            m = fmaxf(m, __shfl_xor(m, 16));
            m = fmaxf(m, __shfl_xor(m, 32));
            float s = 0.f;
            #pragma unroll
            for (int mi = 0; mi < 4; ++mi)
                #pragma unroll
                for (int r = 0; r < 4; ++r) {
                    float e = __expf(acc_s[mi][ni][r] - m);
                    acc_s[mi][ni][r] = e;
                    s += e;
                }
            s += __shfl_xor(s, 16);
            s += __shfl_xor(s, 32);

            int pcol = p0c + w * 32 + ni * 16 + l15;
            float av = att_s[(((size_t)(n * G_ + g)) * P_) + pcol];  // pre-sigmoided
            float scale = av / s;

            #pragma unroll
            for (int mi = 0; mi < 4; ++mi)
                #pragma unroll
                for (int r = 0; r < 4; ++r) {
                    float wv = acc_s[mi][ni][r] * scale;
                    wsp[mi * 4 + r] += wv;
                    wlds[(mi * 16 + q * 4 + r) * 136 + (w * 32 + ni * 16 + l15)] = (short)f2b(wv);
                }
        }

        // ---- agg in two 64-pixel halves: stage xglds_h then 2 pk MFMAs ----
        for (int h = 0; h < 2; ++h) {
            // 128 rows x 9 chunks (72 shorts incl. 8-short pad) = 1152 chunks
            #pragma unroll
            for (int i = 0; i < 4; ++i) {
                int ch = i * 256 + t;
                int row = ch / 9, col = (ch % 9) * 8;
                gl_lds16(&xe[((size_t)(n * E_ + g * 128 + row)) * P_ + p0c + h * 64 + col],
                         &xglds[ch * 8]);
            }
            if (t < 128) {
                int ch = 1024 + t;
                int row = ch / 9, col = (ch % 9) * 8;
                gl_lds16(&xe[((size_t)(n * E_ + g * 128 + row)) * P_ + p0c + h * 64 + col],
                         &xglds[ch * 8]);
            }
            __syncthreads();   // also covers wlds visibility (h=0)

            #pragma unroll
            for (int pk = 0; pk < 2; ++pk) {
                bf16x8 a2[4], b2[2];
                #pragma unroll
                for (int mi = 0; mi < 4; ++mi)
                    a2[mi] = *(const bf16x8*)&wlds[(mi * 16 + l15) * 136 + h * 64 + pk * 32 + q * 8];
                #pragma unroll
                for (int ni = 0; ni < 2; ++ni)
                    b2[ni] = *(const bf16x8*)&xglds[(w * 32 + ni * 16 + l15) * 72 + pk * 32 + q * 8];
                #pragma unroll
                for (int mi = 0; mi < 4; ++mi)
                    #pragma unroll
                    for (int ni = 0; ni < 2; ++ni)
                        acc_a[mi][ni] = __builtin_amdgcn_mfma_f32_16x16x32_bf16(a2[mi], b2[ni], acc_a[mi][ni], 0, 0, 0);
            }
            __syncthreads();
        }
    }

    // ---- epilogue: atomic accumulate ----
    size_t base = ((size_t)(n * G_ + g)) * 64;
    #pragma unroll
    for (int mi = 0; mi < 4; ++mi)
        #pragma unroll
        for (int ni = 0; ni < 2; ++ni)
            #pragma unroll
            for (int r = 0; r < 4; ++r) {
                int k = mi * 16 + q * 4 + r;
                int d = w * 32 + ni * 16 + l15;
                atomicAdd(&agg[(base + k) * 128 + d], acc_a[mi][ni][r]);
            }

    #pragma unroll
    for (int j = 0; j < 16; ++j) {
        float v = wsp[j];
        v += __shfl_xor(v, 1);
        v += __shfl_xor(v, 2);
        v += __shfl_xor(v, 4);
        v += __shfl_xor(v, 8);
        if (l15 == 0) {
            int k = (j >> 2) * 16 + q * 4 + (j & 3);
            atomicAdd(&wsum[base + k], v);
        }
    }
}

// ---------------------------------------------------------------------------
// K5: vlad[n][k][d] = sum_g agg - (sum_g wsum) * centroids
__global__ __launch_bounds__(256) void k5_final(const float* __restrict__ agg,
                                                const float* __restrict__ wsum,
                                                const float* __restrict__ centroids,
                                                float* __restrict__ out) {
    int idx = blockIdx.x * 256 + threadIdx.x;   // grid 1024 -> 262144 exactly
    int d = idx & 127;
    int k = (idx >> 7) & 63;
    int n = idx >> 13;
    float ws = 0.f, ag = 0.f;
    #pragma unroll
    for (int g = 0; g < 8; ++g) {
        size_t base = ((size_t)(n * G_ + g)) * 64 + k;
        ws += wsum[base];
        ag += agg[base * 128 + d];
    }
    out[idx] = ag - ws * centroids[k * 128 + d];
}

// ---------------------------------------------------------------------------
extern "C" void kernel_launch(void* const* d_in, const int* in_sizes, int n_in,
                              void* d_out, int out_size, void* d_ws, size_t ws_size,
                              hipStream_t stream) {
    const float* x         = (const float*)d_in[0];
    const float* W1        = (const float*)d_in[1];
    const float* W2        = (const float*)d_in[2];
    const float* Wc        = (const float*)d_in[3];
    const float* centroids = (const float*)d_in[4];
    float* out = (float*)d_out;

    // Workspace layout (total 120,061,952 B == R3-proven footprint):
    //   W1b      [E*C]        bf16   1,048,576 B @ 0
    //   Vb       [G*K*C]      bf16     524,288 B @ 1,048,576
    //   xhat_t   [N*P*C]      bf16  33,554,432 B @ 1,572,864
    //   xe       [N*E*P]      bf16  67,108,864 B @ 35,127,296
    //   att_s    [N*G*P]      f32    1,048,576 B @ 102,236,160
    //   att_part [N*16*G*P]   f32   16,777,216 B @ 103,284,736 (dead after k3b)
    //   agg      [N*G*K*D]    f32    8,388,608 B @ 103,284,736 (aliases att_part; memset after k3b)
    //   wsum     [N*G*K]      f32      262,144... -> 65,536 B  @ 111,673,344 (inside att_part tail)
    char* ws = (char*)d_ws;
    unsigned short* W1b    = (unsigned short*)(ws + 0);
    unsigned short* Vb     = (unsigned short*)(ws + 1048576);
    unsigned short* xhat_t = (unsigned short*)(ws + 1572864);
    unsigned short* xe     = (unsigned short*)(ws + 35127296);
    float*          att_s  = (float*)(ws + 102236160);
    float*          att_part = (float*)(ws + 103284736);
    float*          agg    = (float*)(ws + 103284736);
    float*          wsum   = (float*)(ws + 111673344);

    hipLaunchKernelGGL(k0_prep,        dim3(1024), dim3(256), 0, stream, W1, Wc, W1b, Vb);
    hipLaunchKernelGGL(k1_norm_transpose, dim3(16, 32), dim3(256), 0, stream, x, xhat_t);
    hipLaunchKernelGGL(k2_gemm_xe,     dim3(64, 32), dim3(256), 0, stream, W1b, xhat_t, xe);
    hipLaunchKernelGGL(k3a_att_part,   dim3(16, 32), dim3(256), 0, stream, xe, W2, att_part);
    hipLaunchKernelGGL(k3b_att_reduce, dim3(1024), dim3(256), 0, stream, att_part, att_s);
    // zero agg+wsum (att_part is dead now; regions overlap its space)
    hipMemsetAsync(ws + 103284736, 0, 8388608 + 65536, stream);
    hipLaunchKernelGGL(k4_assign_agg,  dim3(32, 32), dim3(256), 0, stream, Vb, xhat_t, xe,
                       att_s, agg, wsum);
    hipLaunchKernelGGL(k5_final,       dim3(1024), dim3(256), 0, stream,
                       agg, wsum, centroids, out);
}

// Round 5
// 262.738 us; speedup vs baseline: 1.0637x; 1.0637x over previous
//
#include <hip/hip_runtime.h>

// ---------------------------------------------------------------------------
// TransVLAD fused pipeline for MI355X (gfx950)
// Shapes: N=32, C=512, H=W=32 (P=1024), E=1024, G=8, D=128, K=64
// out: [N, K*D] fp32 (262144)
//
// R5: R4's atomics-based K4 regressed (64->98.7us: 8.4M device atomics w/
// 4-way cross-XCD contention doubled WRITE_SIZE and serialized block exit).
// Revert K4 to R3 structure (partials, no atomics) + alias LDS regions
// (S-phase tiles overlap xglds; 63KB -> 51KB -> 3 blocks/CU).
// Keep R4's K1 single-read + K3a vectorization (net -18us); fold k0 into k1.
// ---------------------------------------------------------------------------

#define N_  32
#define C_  512
#define P_  1024
#define E_  1024
#define G_  8
#define D_  128
#define K_  64

typedef __attribute__((ext_vector_type(8))) short bf16x8;
typedef __attribute__((ext_vector_type(4))) float f32x4;

__device__ __forceinline__ unsigned short f2b(float f) {
    union { float f; unsigned u; } v; v.f = f;
    unsigned r = (v.u + 0x7FFFu + ((v.u >> 16) & 1u)) >> 16;
    return (unsigned short)r;
}
__device__ __forceinline__ float b2f(unsigned short h) {
    union { unsigned u; float f; } v; v.u = ((unsigned)h) << 16;
    return v.f;
}

// async global->LDS 16B copy: LDS dest must be wave-uniform base + lane*16
__device__ __forceinline__ void gl_lds16(const void* g, void* l) {
    __builtin_amdgcn_global_load_lds(
        (const __attribute__((address_space(1))) void*)g,
        (__attribute__((address_space(3))) void*)l, 16, 0, 0);
}

// ---------------------------------------------------------------------------
// K1+K0 merged. grid (48, 32):
//   bx < 16 : K1 = per-pixel L2 norm + transpose -> xhat_t [N][P][C] bf16
//   bx >= 16: K0 = W1->bf16 convert + V = Wc*W1_g -> Vb [G*K][C] bf16
__global__ __launch_bounds__(256) void k1_norm_prep(const float* __restrict__ x,
                                                    const float* __restrict__ W1,
                                                    const float* __restrict__ Wc,
                                                    unsigned short* __restrict__ xhat_t,
                                                    unsigned short* __restrict__ W1b,
                                                    unsigned short* __restrict__ Vb) {
    __shared__ short xc[128 * 256];   // [i][t]: c = (t>>6)*128+i, p = p0+(t&63)
    __shared__ float red[256];
    __shared__ float rn[64];
    int t = threadIdx.x;

    if (blockIdx.x >= 16) {
        // ---- K0 work: bid in 0..1023 ----
        int bid = (blockIdx.x - 16) * 32 + blockIdx.y;
        int i0 = bid * 512 + t;
        W1b[i0]       = f2b(W1[i0]);
        W1b[i0 + 256] = f2b(W1[i0 + 256]);
        int ch = bid & 1, k = (bid >> 1) & 63, g = bid >> 7;
        int c = ch * 256 + t;
        float acc = 0.f;
        #pragma unroll 8
        for (int d = 0; d < 128; ++d)
            acc += Wc[k * 128 + d] * W1[(g * 128 + d) * C_ + c];
        Vb[(g * 64 + k) * C_ + c] = f2b(acc);
        return;
    }

    // ---- K1 work ----
    int n = blockIdx.y;
    int p0 = blockIdx.x * 64;
    int ps = t & 63, cs = t >> 6;

    float ss = 0.f;
    for (int i = 0; i < 128; ++i) {
        float v = x[((size_t)(n * C_ + cs * 128 + i)) * P_ + p0 + ps];
        ss += v * v;
        xc[i * 256 + t] = (short)f2b(v);     // lanes consecutive -> conflict-free
    }
    red[t] = ss;
    __syncthreads();
    if (t < 64) {
        float s = red[t] + red[64 + t] + red[128 + t] + red[192 + t];
        rn[t] = 1.0f / fmaxf(sqrtf(s), 1e-12f);
    }
    __syncthreads();

    float r = rn[ps];
    size_t base = ((size_t)(n * P_ + p0 + ps)) * C_ + cs * 128;
    #pragma unroll
    for (int jj = 0; jj < 16; ++jj) {
        bf16x8 o;
        #pragma unroll
        for (int j = 0; j < 8; ++j)
            o[j] = (short)f2b(b2f((unsigned short)xc[(jj * 8 + j) * 256 + t]) * r);
        *(bf16x8*)&xhat_t[base + jj * 8] = o;   // 256B/thread region; L2 merges
    }
}

// ---------------------------------------------------------------------------
// K2: xe[n][e][p] = sum_c W1b[e][c] * xhat_t[n][p][c]   (bf16 MFMA GEMM, NT)
// grid (64, 32): e0 = (bx>>3)*128, p0 = (bx&7)*128, n = by. 256 thr = 4 waves.
__global__ __launch_bounds__(256) void k2_gemm_xe(const unsigned short* __restrict__ W1b,
                                                  const unsigned short* __restrict__ xhat_t,
                                                  unsigned short* __restrict__ xe) {
    __shared__ __align__(16) short As[128 * 32];
    __shared__ __align__(16) short Bs[128 * 32];
    int n = blockIdx.y;
    int e0 = (blockIdx.x >> 3) * 128;
    int p0 = (blockIdx.x & 7) * 128;
    int t = threadIdx.x;
    int w = t >> 6, l = t & 63, q = l >> 4, l15 = l & 15;
    int wr = w >> 1, wc = w & 1;

    f32x4 acc[4][4];
    #pragma unroll
    for (int mi = 0; mi < 4; ++mi)
        #pragma unroll
        for (int ni = 0; ni < 4; ++ni)
            acc[mi][ni] = (f32x4){0.f, 0.f, 0.f, 0.f};

    for (int ks = 0; ks < 16; ++ks) {
        int k0 = ks * 32;
        #pragma unroll
        for (int i = 0; i < 2; ++i) {
            int ch = i * 256 + t;
            int row = ch >> 2, col = (ch & 3) * 8;
            gl_lds16(&W1b[(e0 + row) * C_ + k0 + col], &As[ch * 8]);
        }
        #pragma unroll
        for (int i = 0; i < 2; ++i) {
            int ch = i * 256 + t;
            int row = ch >> 2, col = (ch & 3) * 8;
            gl_lds16(&xhat_t[((size_t)(n * P_ + p0 + row)) * C_ + k0 + col], &Bs[ch * 8]);
        }
        __syncthreads();

        bf16x8 af[4], bf[4];
        #pragma unroll
        for (int mi = 0; mi < 4; ++mi)
            af[mi] = *(const bf16x8*)&As[(wr * 64 + mi * 16 + l15) * 32 + q * 8];
        #pragma unroll
        for (int ni = 0; ni < 4; ++ni)
            bf[ni] = *(const bf16x8*)&Bs[(wc * 64 + ni * 16 + l15) * 32 + q * 8];
        #pragma unroll
        for (int mi = 0; mi < 4; ++mi)
            #pragma unroll
            for (int ni = 0; ni < 4; ++ni)
                acc[mi][ni] = __builtin_amdgcn_mfma_f32_16x16x32_bf16(af[mi], bf[ni], acc[mi][ni], 0, 0, 0);
        __syncthreads();
    }

    #pragma unroll
    for (int mi = 0; mi < 4; ++mi) {
        #pragma unroll
        for (int ni = 0; ni < 4; ++ni) {
            #pragma unroll
            for (int r = 0; r < 4; ++r) {
                int e = e0 + wr * 64 + mi * 16 + q * 4 + r;
                int p = p0 + wc * 64 + ni * 16 + l15;
                xe[((size_t)(n * E_ + e)) * P_ + p] = f2b(acc[mi][ni][r]);
            }
        }
    }
}

// ---------------------------------------------------------------------------
// K3a: att partials over 64-wide e-chunks, 4 pixels/thread (ushort4/float4).
// grid (16, 32): ec = bx (0..15); n = by. p = t*4 .. t*4+3.
__global__ __launch_bounds__(256) void k3a_att_part(const unsigned short* __restrict__ xe,
                                                    const float* __restrict__ W2,
                                                    float* __restrict__ att_part) {
    int n = blockIdx.y;
    int ec = blockIdx.x;
    int t = threadIdx.x;
    int e0 = ec * 64;
    f32x4 acc[8];
    #pragma unroll
    for (int g = 0; g < 8; ++g) acc[g] = (f32x4){0.f, 0.f, 0.f, 0.f};
    #pragma unroll 4
    for (int i = 0; i < 64; ++i) {
        int e = e0 + i;
        ushort4 v4 = *(const ushort4*)&xe[((size_t)(n * E_ + e)) * P_ + t * 4];
        f32x4 vf = {b2f(v4.x), b2f(v4.y), b2f(v4.z), b2f(v4.w)};
        #pragma unroll
        for (int g = 0; g < 8; ++g)
            acc[g] += vf * W2[g * E_ + e];         // wave-uniform s_load
    }
    #pragma unroll
    for (int g = 0; g < 8; ++g)
        *(f32x4*)&att_part[(((size_t)(n * 16 + ec)) * 8 + g) * P_ + t * 4] = acc[g];
}

// K3b: att_s[n][g][p] = sigmoid( sum_ec att_part[n][ec][g][p] )
__global__ __launch_bounds__(256) void k3b_att_reduce(const float* __restrict__ att_part,
                                                      float* __restrict__ att_s) {
    int idx = blockIdx.x * 256 + threadIdx.x;   // grid 1024 -> 262144 exactly
    int p = idx & 1023;
    int g = (idx >> 10) & 7;
    int n = idx >> 13;
    float s = 0.f;
    #pragma unroll
    for (int ec = 0; ec < 16; ++ec)
        s += att_part[(((size_t)(n * 16 + ec)) * 8 + g) * P_ + p];
    att_s[idx] = 1.0f / (1.0f + __expf(-s));
}

// ---------------------------------------------------------------------------
// K4: fused assignment -> softmax -> gate -> aggregation per (n, g, ph)
// grid (16, 32): g = bx&7, ph = bx>>3, n = by. 256 thr = 4 waves.
// LDS aliased: region0 = S-phase tiles (As2 4K + Bs2 8K) OR xglds (34K);
// wlds (17K) separate. Total 52224 B -> 3 blocks/CU.
__global__ __launch_bounds__(256) void k4_assign_agg(const unsigned short* __restrict__ Vb,
                                                     const unsigned short* __restrict__ xhat_t,
                                                     const unsigned short* __restrict__ xe,
                                                     const float* __restrict__ att_s,
                                                     float* __restrict__ agg_part,
                                                     float* __restrict__ wsum_part) {
    __shared__ __align__(16) char smem[34816 + 17408];
    short* xglds = (short*)smem;                    // [128][136]  (agg phase)
    short* As2   = (short*)smem;                    // [64][32]    (S phase)
    short* Bs2   = (short*)(smem + 4096);           // [128][32]   (S phase)
    short* wlds  = (short*)(smem + 34816);          // [64][136]

    int g = blockIdx.x & 7, ph = blockIdx.x >> 3, n = blockIdx.y;
    int t = threadIdx.x;
    int w = t >> 6, l = t & 63, q = l >> 4, l15 = l & 15;

    f32x4 acc_a[4][2];
    #pragma unroll
    for (int mi = 0; mi < 4; ++mi)
        #pragma unroll
        for (int ni = 0; ni < 2; ++ni)
            acc_a[mi][ni] = (f32x4){0.f, 0.f, 0.f, 0.f};
    float wsp[16];
    #pragma unroll
    for (int j = 0; j < 16; ++j) wsp[j] = 0.f;

    for (int cc = 0; cc < 4; ++cc) {
        int p0c = ph * 512 + cc * 128;

        // ---- Phase S: S = Vb[g] (64xC) * xhat^T (Cx128) ----
        f32x4 acc_s[4][2];
        #pragma unroll
        for (int mi = 0; mi < 4; ++mi)
            #pragma unroll
            for (int ni = 0; ni < 2; ++ni)
                acc_s[mi][ni] = (f32x4){0.f, 0.f, 0.f, 0.f};

        for (int ks = 0; ks < 16; ++ks) {
            int k0 = ks * 32;
            {   // As2: 64x32, 1 chunk/thread
                int row = t >> 2, col = (t & 3) * 8;
                gl_lds16(&Vb[(g * 64 + row) * C_ + k0 + col], &As2[t * 8]);
            }
            #pragma unroll
            for (int i = 0; i < 2; ++i) {   // Bs2: 128x32
                int ch = i * 256 + t;
                int row = ch >> 2, col = (ch & 3) * 8;
                gl_lds16(&xhat_t[((size_t)(n * P_ + p0c + row)) * C_ + k0 + col], &Bs2[ch * 8]);
            }
            __syncthreads();
            bf16x8 af[4], bf2[2];
            #pragma unroll
            for (int mi = 0; mi < 4; ++mi)
                af[mi] = *(const bf16x8*)&As2[(mi * 16 + l15) * 32 + q * 8];
            #pragma unroll
            for (int ni = 0; ni < 2; ++ni)
                bf2[ni] = *(const bf16x8*)&Bs2[(w * 32 + ni * 16 + l15) * 32 + q * 8];
            #pragma unroll
            for (int mi = 0; mi < 4; ++mi)
                #pragma unroll
                for (int ni = 0; ni < 2; ++ni)
                    acc_s[mi][ni] = __builtin_amdgcn_mfma_f32_16x16x32_bf16(af[mi], bf2[ni], acc_s[mi][ni], 0, 0, 0);
            __syncthreads();
        }

        // ---- softmax over k + gate (writes wlds only) ----
        #pragma unroll
        for (int ni = 0; ni < 2; ++ni) {
            float m = -1e30f;
            #pragma unroll
            for (int mi = 0; mi < 4; ++mi)
                #pragma unroll
                for (int r = 0; r < 4; ++r)
                    m = fmaxf(m, acc_s[mi][ni][r]);
            m = fmaxf(m, __shfl_xor(m, 16));
            m = fmaxf(m, __shfl_xor(m, 32));
            float s = 0.f;
            #pragma unroll
            for (int mi = 0; mi < 4; ++mi)
                #pragma unroll
                for (int r = 0; r < 4; ++r) {
                    float e = __expf(acc_s[mi][ni][r] - m);
                    acc_s[mi][ni][r] = e;
                    s += e;
                }
            s += __shfl_xor(s, 16);
            s += __shfl_xor(s, 32);

            int pcol = p0c + w * 32 + ni * 16 + l15;
            float av = att_s[(((size_t)(n * G_ + g)) * P_) + pcol];  // pre-sigmoided
            float scale = av / s;

            #pragma unroll
            for (int mi = 0; mi < 4; ++mi)
                #pragma unroll
                for (int r = 0; r < 4; ++r) {
                    float wv = acc_s[mi][ni][r] * scale;
                    wsp[mi * 4 + r] += wv;
                    wlds[(mi * 16 + q * 4 + r) * 136 + (w * 32 + ni * 16 + l15)] = (short)f2b(wv);
                }
        }

        // ---- stage xg (d-major) async into region0 (As2/Bs2 dead now) ----
        // 128*136 shorts = 2176 16B-chunks: 8 full rounds + half round
        #pragma unroll
        for (int i = 0; i < 8; ++i) {
            int ch = i * 256 + t;
            int row = ch / 17, col = (ch % 17) * 8;
            gl_lds16(&xe[((size_t)(n * E_ + g * 128 + row)) * P_ + p0c + col], &xglds[ch * 8]);
        }
        if (t < 128) {
            int ch = 2048 + t;
            int row = ch / 17, col = (ch % 17) * 8;
            gl_lds16(&xe[((size_t)(n * E_ + g * 128 + row)) * P_ + p0c + col], &xglds[ch * 8]);
        }
        __syncthreads();   // covers wlds writes + xglds staging

        // ---- agg MFMA: A = w [64k x 128p], B = xg [128d x 128p] (NT) ----
        #pragma unroll
        for (int pk = 0; pk < 4; ++pk) {
            bf16x8 a2[4], b2[2];
            #pragma unroll
            for (int mi = 0; mi < 4; ++mi)
                a2[mi] = *(const bf16x8*)&wlds[(mi * 16 + l15) * 136 + pk * 32 + q * 8];
            #pragma unroll
            for (int ni = 0; ni < 2; ++ni)
                b2[ni] = *(const bf16x8*)&xglds[(w * 32 + ni * 16 + l15) * 136 + pk * 32 + q * 8];
            #pragma unroll
            for (int mi = 0; mi < 4; ++mi)
                #pragma unroll
                for (int ni = 0; ni < 2; ++ni)
                    acc_a[mi][ni] = __builtin_amdgcn_mfma_f32_16x16x32_bf16(a2[mi], b2[ni], acc_a[mi][ni], 0, 0, 0);
        }
        __syncthreads();   // xglds reads done before next cc's As2/Bs2 staging
    }

    // ---- epilogue: disjoint partials, no atomics ----
    size_t base = (((size_t)(n * G_ + g)) * 2 + ph) * 64;
    #pragma unroll
    for (int mi = 0; mi < 4; ++mi)
        #pragma unroll
        for (int ni = 0; ni < 2; ++ni)
            #pragma unroll
            for (int r = 0; r < 4; ++r) {
                int k = mi * 16 + q * 4 + r;
                int d = w * 32 + ni * 16 + l15;
                agg_part[(base + k) * 128 + d] = acc_a[mi][ni][r];
            }

    #pragma unroll
    for (int j = 0; j < 16; ++j) {
        float v = wsp[j];
        v += __shfl_xor(v, 1);
        v += __shfl_xor(v, 2);
        v += __shfl_xor(v, 4);
        v += __shfl_xor(v, 8);
        if (l15 == 0) {
            int k = (j >> 2) * 16 + q * 4 + (j & 3);
            wsum_part[((((size_t)(n * G_ + g)) * 2 + ph) * 4 + w) * 64 + k] = v;
        }
    }
}

// ---------------------------------------------------------------------------
// K5: vlad[n][k][d] = sum_{g,ph} agg_part - (sum) * centroids
__global__ __launch_bounds__(256) void k5_final(const float* __restrict__ agg_part,
                                                const float* __restrict__ wsum_part,
                                                const float* __restrict__ centroids,
                                                float* __restrict__ out) {
    int idx = blockIdx.x * 256 + threadIdx.x;   // grid 1024 -> 262144 exactly
    int d = idx & 127;
    int k = (idx >> 7) & 63;
    int n = idx >> 13;
    float ws = 0.f;
    #pragma unroll
    for (int g = 0; g < 8; ++g)
        #pragma unroll
        for (int ph = 0; ph < 2; ++ph)
            #pragma unroll
            for (int w2 = 0; w2 < 4; ++w2)
                ws += wsum_part[((((size_t)(n * G_ + g)) * 2 + ph) * 4 + w2) * 64 + k];
    float agg = 0.f;
    #pragma unroll
    for (int g = 0; g < 8; ++g)
        #pragma unroll
        for (int ph = 0; ph < 2; ++ph)
            agg += agg_part[(((((size_t)(n * G_ + g)) * 2 + ph) * 64) + k) * 128 + d];
    out[idx] = agg - ws * centroids[k * 128 + d];
}

// ---------------------------------------------------------------------------
extern "C" void kernel_launch(void* const* d_in, const int* in_sizes, int n_in,
                              void* d_out, int out_size, void* d_ws, size_t ws_size,
                              hipStream_t stream) {
    const float* x         = (const float*)d_in[0];
    const float* W1        = (const float*)d_in[1];
    const float* W2        = (const float*)d_in[2];
    const float* Wc        = (const float*)d_in[3];
    const float* centroids = (const float*)d_in[4];
    float* out = (float*)d_out;

    // Workspace layout (total 120,324,096 B == R2/R3-proven footprint):
    //   W1b      [E*C]        bf16   1,048,576 B @ 0
    //   Vb       [G*K*C]      bf16     524,288 B @ 1,048,576
    //   xhat_t   [N*P*C]      bf16  33,554,432 B @ 1,572,864
    //   xe       [N*E*P]      bf16  67,108,864 B @ 35,127,296
    //   att_s    [N*G*P]      f32    1,048,576 B @ 102,236,160
    //   att_part [N*16*G*P]   f32   16,777,216 B @ 103,284,736 (dead after k3b;
    //   agg_part [N*G*2*K*D]  f32   16,777,216 B @ 103,284,736  aliases att_part)
    //   wsum_part[N*G*2*4*K]  f32      262,144 B @ 120,061,952
    char* ws = (char*)d_ws;
    unsigned short* W1b      = (unsigned short*)(ws + 0);
    unsigned short* Vb       = (unsigned short*)(ws + 1048576);
    unsigned short* xhat_t   = (unsigned short*)(ws + 1572864);
    unsigned short* xe       = (unsigned short*)(ws + 35127296);
    float*          att_s    = (float*)(ws + 102236160);
    float*          att_part = (float*)(ws + 103284736);
    float*          agg_part = (float*)(ws + 103284736);   // alias: att_part dead before K4
    float*          wsum_part= (float*)(ws + 120061952);

    hipLaunchKernelGGL(k1_norm_prep,   dim3(48, 32), dim3(256), 0, stream,
                       x, W1, Wc, xhat_t, W1b, Vb);
    hipLaunchKernelGGL(k2_gemm_xe,     dim3(64, 32), dim3(256), 0, stream, W1b, xhat_t, xe);
    hipLaunchKernelGGL(k3a_att_part,   dim3(16, 32), dim3(256), 0, stream, xe, W2, att_part);
    hipLaunchKernelGGL(k3b_att_reduce, dim3(1024), dim3(256), 0, stream, att_part, att_s);
    hipLaunchKernelGGL(k4_assign_agg,  dim3(16, 32), dim3(256), 0, stream, Vb, xhat_t, xe,
                       att_s, agg_part, wsum_part);
    hipLaunchKernelGGL(k5_final,       dim3(1024), dim3(256), 0, stream,
                       agg_part, wsum_part, centroids, out);
}

// Round 6
// 253.554 us; speedup vs baseline: 1.1022x; 1.0362x over previous
//
#include <hip/hip_runtime.h>

// ---------------------------------------------------------------------------
// TransVLAD fused pipeline for MI355X (gfx950)
// Shapes: N=32, C=512, H=W=32 (P=1024), E=1024, G=8, D=128, K=64
// out: [N, K*D] fp32 (262144)
//
// R6: (a) un-merge k0 (R5's merge cost ~18us: K0 blocks inherited 65KB LDS
// alloc -> 2 blocks/CU). (b) K4/K2 are barrier-drain bound (nothing >40%):
// BK=32 -> BK=64 halves barrier count; K4 also issues xglds DMA at top of
// each cc so agg staging drains behind S-phase barriers. K4 LDS un-aliased
// 76.8KB (2 blocks/CU, grid-capped anyway).
// ---------------------------------------------------------------------------

#define N_  32
#define C_  512
#define P_  1024
#define E_  1024
#define G_  8
#define D_  128
#define K_  64

typedef __attribute__((ext_vector_type(8))) short bf16x8;
typedef __attribute__((ext_vector_type(4))) float f32x4;

__device__ __forceinline__ unsigned short f2b(float f) {
    union { float f; unsigned u; } v; v.f = f;
    unsigned r = (v.u + 0x7FFFu + ((v.u >> 16) & 1u)) >> 16;
    return (unsigned short)r;
}
__device__ __forceinline__ float b2f(unsigned short h) {
    union { unsigned u; float f; } v; v.u = ((unsigned)h) << 16;
    return v.f;
}

// async global->LDS 16B copy: LDS dest must be wave-uniform base + lane*16
__device__ __forceinline__ void gl_lds16(const void* g, void* l) {
    __builtin_amdgcn_global_load_lds(
        (const __attribute__((address_space(1))) void*)g,
        (__attribute__((address_space(3))) void*)l, 16, 0, 0);
}

// ---------------------------------------------------------------------------
// K0: convert W1 -> bf16 AND build V[g][k][c] = sum_d Wc[k][d]*W1[g*128+d][c]
// grid 1024. No LDS -> high occupancy (12 VGPR in R4).
__global__ __launch_bounds__(256) void k0_prep(const float* __restrict__ W1,
                                               const float* __restrict__ Wc,
                                               unsigned short* __restrict__ W1b,
                                               unsigned short* __restrict__ Vb) {
    int bid = blockIdx.x;
    int t = threadIdx.x;
    int i0 = bid * 512 + t;
    W1b[i0]       = f2b(W1[i0]);
    W1b[i0 + 256] = f2b(W1[i0 + 256]);
    int ch = bid & 1, k = (bid >> 1) & 63, g = bid >> 7;
    int c = ch * 256 + t;
    float acc = 0.f;
    #pragma unroll 8
    for (int d = 0; d < 128; ++d)
        acc += Wc[k * 128 + d] * W1[(g * 128 + d) * C_ + c];
    Vb[(g * 64 + k) * C_ + c] = f2b(acc);
}

// ---------------------------------------------------------------------------
// K1: per-pixel L2 norm over C, write x_hat transposed: xhat_t [N][P][C] bf16
// grid (16,32): p0 = bx*64, n = by. Single global read of x via bf16 LDS cache.
__global__ __launch_bounds__(256) void k1_norm_transpose(const float* __restrict__ x,
                                                         unsigned short* __restrict__ xhat_t) {
    __shared__ short xc[128 * 256];   // [i][t]: c = (t>>6)*128+i, p = p0+(t&63)
    __shared__ float red[256];
    __shared__ float rn[64];
    int n = blockIdx.y;
    int p0 = blockIdx.x * 64;
    int t = threadIdx.x;
    int ps = t & 63, cs = t >> 6;

    float ss = 0.f;
    for (int i = 0; i < 128; ++i) {
        float v = x[((size_t)(n * C_ + cs * 128 + i)) * P_ + p0 + ps];
        ss += v * v;
        xc[i * 256 + t] = (short)f2b(v);     // lanes consecutive -> conflict-free
    }
    red[t] = ss;
    __syncthreads();
    if (t < 64) {
        float s = red[t] + red[64 + t] + red[128 + t] + red[192 + t];
        rn[t] = 1.0f / fmaxf(sqrtf(s), 1e-12f);
    }
    __syncthreads();

    float r = rn[ps];
    size_t base = ((size_t)(n * P_ + p0 + ps)) * C_ + cs * 128;
    #pragma unroll
    for (int jj = 0; jj < 16; ++jj) {
        bf16x8 o;
        #pragma unroll
        for (int j = 0; j < 8; ++j)
            o[j] = (short)f2b(b2f((unsigned short)xc[(jj * 8 + j) * 256 + t]) * r);
        *(bf16x8*)&xhat_t[base + jj * 8] = o;
    }
}

// ---------------------------------------------------------------------------
// K2: xe[n][e][p] = sum_c W1b[e][c] * xhat_t[n][p][c]   (bf16 MFMA GEMM, NT)
// grid (64, 32). BK=64: 8 staging rounds (was 16) -> half the barrier drains.
__global__ __launch_bounds__(256) void k2_gemm_xe(const unsigned short* __restrict__ W1b,
                                                  const unsigned short* __restrict__ xhat_t,
                                                  unsigned short* __restrict__ xe) {
    __shared__ __align__(16) short As[128 * 64];
    __shared__ __align__(16) short Bs[128 * 64];
    int n = blockIdx.y;
    int e0 = (blockIdx.x >> 3) * 128;
    int p0 = (blockIdx.x & 7) * 128;
    int t = threadIdx.x;
    int w = t >> 6, l = t & 63, q = l >> 4, l15 = l & 15;
    int wr = w >> 1, wc = w & 1;

    f32x4 acc[4][4];
    #pragma unroll
    for (int mi = 0; mi < 4; ++mi)
        #pragma unroll
        for (int ni = 0; ni < 4; ++ni)
            acc[mi][ni] = (f32x4){0.f, 0.f, 0.f, 0.f};

    for (int ks = 0; ks < 8; ++ks) {
        int k0 = ks * 64;
        // As: 128 rows x 8 chunks = 1024 chunks, 4/thread
        #pragma unroll
        for (int i = 0; i < 4; ++i) {
            int ch = i * 256 + t;
            int row = ch >> 3, col = (ch & 7) * 8;
            gl_lds16(&W1b[(e0 + row) * C_ + k0 + col], &As[ch * 8]);
        }
        #pragma unroll
        for (int i = 0; i < 4; ++i) {
            int ch = i * 256 + t;
            int row = ch >> 3, col = (ch & 7) * 8;
            gl_lds16(&xhat_t[((size_t)(n * P_ + p0 + row)) * C_ + k0 + col], &Bs[ch * 8]);
        }
        __syncthreads();

        #pragma unroll
        for (int kk = 0; kk < 2; ++kk) {
            bf16x8 af[4], bf[4];
            #pragma unroll
            for (int mi = 0; mi < 4; ++mi)
                af[mi] = *(const bf16x8*)&As[(wr * 64 + mi * 16 + l15) * 64 + kk * 32 + q * 8];
            #pragma unroll
            for (int ni = 0; ni < 4; ++ni)
                bf[ni] = *(const bf16x8*)&Bs[(wc * 64 + ni * 16 + l15) * 64 + kk * 32 + q * 8];
            #pragma unroll
            for (int mi = 0; mi < 4; ++mi)
                #pragma unroll
                for (int ni = 0; ni < 4; ++ni)
                    acc[mi][ni] = __builtin_amdgcn_mfma_f32_16x16x32_bf16(af[mi], bf[ni], acc[mi][ni], 0, 0, 0);
        }
        __syncthreads();
    }

    #pragma unroll
    for (int mi = 0; mi < 4; ++mi) {
        #pragma unroll
        for (int ni = 0; ni < 4; ++ni) {
            #pragma unroll
            for (int r = 0; r < 4; ++r) {
                int e = e0 + wr * 64 + mi * 16 + q * 4 + r;
                int p = p0 + wc * 64 + ni * 16 + l15;
                xe[((size_t)(n * E_ + e)) * P_ + p] = f2b(acc[mi][ni][r]);
            }
        }
    }
}

// ---------------------------------------------------------------------------
// K3a: att partials over 64-wide e-chunks, 4 pixels/thread (ushort4/float4).
__global__ __launch_bounds__(256) void k3a_att_part(const unsigned short* __restrict__ xe,
                                                    const float* __restrict__ W2,
                                                    float* __restrict__ att_part) {
    int n = blockIdx.y;
    int ec = blockIdx.x;
    int t = threadIdx.x;
    int e0 = ec * 64;
    f32x4 acc[8];
    #pragma unroll
    for (int g = 0; g < 8; ++g) acc[g] = (f32x4){0.f, 0.f, 0.f, 0.f};
    #pragma unroll 4
    for (int i = 0; i < 64; ++i) {
        int e = e0 + i;
        ushort4 v4 = *(const ushort4*)&xe[((size_t)(n * E_ + e)) * P_ + t * 4];
        f32x4 vf = {b2f(v4.x), b2f(v4.y), b2f(v4.z), b2f(v4.w)};
        #pragma unroll
        for (int g = 0; g < 8; ++g)
            acc[g] += vf * W2[g * E_ + e];
    }
    #pragma unroll
    for (int g = 0; g < 8; ++g)
        *(f32x4*)&att_part[(((size_t)(n * 16 + ec)) * 8 + g) * P_ + t * 4] = acc[g];
}

// K3b: att_s[n][g][p] = sigmoid( sum_ec att_part[n][ec][g][p] )
__global__ __launch_bounds__(256) void k3b_att_reduce(const float* __restrict__ att_part,
                                                      float* __restrict__ att_s) {
    int idx = blockIdx.x * 256 + threadIdx.x;
    int p = idx & 1023;
    int g = (idx >> 10) & 7;
    int n = idx >> 13;
    float s = 0.f;
    #pragma unroll
    for (int ec = 0; ec < 16; ++ec)
        s += att_part[(((size_t)(n * 16 + ec)) * 8 + g) * P_ + p];
    att_s[idx] = 1.0f / (1.0f + __expf(-s));
}

// ---------------------------------------------------------------------------
// K4: fused assignment -> softmax -> gate -> aggregation per (n, g, ph)
// grid (16, 32). BK=64 S-phase (8 rounds, was 16) + xglds DMA issued at cc
// top (drains behind S-phase barriers). LDS 76.8KB -> 2 blocks/CU (= grid cap).
__global__ __launch_bounds__(256) void k4_assign_agg(const unsigned short* __restrict__ Vb,
                                                     const unsigned short* __restrict__ xhat_t,
                                                     const unsigned short* __restrict__ xe,
                                                     const float* __restrict__ att_s,
                                                     float* __restrict__ agg_part,
                                                     float* __restrict__ wsum_part) {
    __shared__ __align__(16) char smem[8192 + 16384 + 34816 + 17408];
    short* As2   = (short*)smem;                    // [64][64]    8 KB
    short* Bs2   = (short*)(smem + 8192);           // [128][64]   16 KB
    short* xglds = (short*)(smem + 24576);          // [128][136]  34 KB
    short* wlds  = (short*)(smem + 59392);          // [64][136]   17 KB

    int g = blockIdx.x & 7, ph = blockIdx.x >> 3, n = blockIdx.y;
    int t = threadIdx.x;
    int w = t >> 6, l = t & 63, q = l >> 4, l15 = l & 15;

    f32x4 acc_a[4][2];
    #pragma unroll
    for (int mi = 0; mi < 4; ++mi)
        #pragma unroll
        for (int ni = 0; ni < 2; ++ni)
            acc_a[mi][ni] = (f32x4){0.f, 0.f, 0.f, 0.f};
    float wsp[16];
    #pragma unroll
    for (int j = 0; j < 16; ++j) wsp[j] = 0.f;

    for (int cc = 0; cc < 4; ++cc) {
        int p0c = ph * 512 + cc * 128;

        // ---- issue xg staging FIRST (agg input; drains behind S barriers) ----
        // xglds [128][136]: 2176 chunks = 8 full rounds + half round
        #pragma unroll
        for (int i = 0; i < 8; ++i) {
            int ch = i * 256 + t;
            int row = ch / 17, col = (ch % 17) * 8;
            gl_lds16(&xe[((size_t)(n * E_ + g * 128 + row)) * P_ + p0c + col], &xglds[ch * 8]);
        }
        if (t < 128) {
            int ch = 2048 + t;
            int row = ch / 17, col = (ch % 17) * 8;
            gl_lds16(&xe[((size_t)(n * E_ + g * 128 + row)) * P_ + p0c + col], &xglds[ch * 8]);
        }

        // ---- Phase S: S = Vb[g] (64xC) * xhat^T (Cx128), BK=64 ----
        f32x4 acc_s[4][2];
        #pragma unroll
        for (int mi = 0; mi < 4; ++mi)
            #pragma unroll
            for (int ni = 0; ni < 2; ++ni)
                acc_s[mi][ni] = (f32x4){0.f, 0.f, 0.f, 0.f};

        for (int ks = 0; ks < 8; ++ks) {
            int k0 = ks * 64;
            // As2: 64 rows x 8 chunks = 512 chunks, 2/thread
            #pragma unroll
            for (int i = 0; i < 2; ++i) {
                int ch = i * 256 + t;
                int row = ch >> 3, col = (ch & 7) * 8;
                gl_lds16(&Vb[(g * 64 + row) * C_ + k0 + col], &As2[ch * 8]);
            }
            // Bs2: 128 rows x 8 chunks = 1024 chunks, 4/thread
            #pragma unroll
            for (int i = 0; i < 4; ++i) {
                int ch = i * 256 + t;
                int row = ch >> 3, col = (ch & 7) * 8;
                gl_lds16(&xhat_t[((size_t)(n * P_ + p0c + row)) * C_ + k0 + col], &Bs2[ch * 8]);
            }
            __syncthreads();
            #pragma unroll
            for (int kk = 0; kk < 2; ++kk) {
                bf16x8 af[4], bf2[2];
                #pragma unroll
                for (int mi = 0; mi < 4; ++mi)
                    af[mi] = *(const bf16x8*)&As2[(mi * 16 + l15) * 64 + kk * 32 + q * 8];
                #pragma unroll
                for (int ni = 0; ni < 2; ++ni)
                    bf2[ni] = *(const bf16x8*)&Bs2[(w * 32 + ni * 16 + l15) * 64 + kk * 32 + q * 8];
                #pragma unroll
                for (int mi = 0; mi < 4; ++mi)
                    #pragma unroll
                    for (int ni = 0; ni < 2; ++ni)
                        acc_s[mi][ni] = __builtin_amdgcn_mfma_f32_16x16x32_bf16(af[mi], bf2[ni], acc_s[mi][ni], 0, 0, 0);
            }
            __syncthreads();
        }

        // ---- softmax over k + gate (writes wlds only) ----
        #pragma unroll
        for (int ni = 0; ni < 2; ++ni) {
            float m = -1e30f;
            #pragma unroll
            for (int mi = 0; mi < 4; ++mi)
                #pragma unroll
                for (int r = 0; r < 4; ++r)
                    m = fmaxf(m, acc_s[mi][ni][r]);
            m = fmaxf(m, __shfl_xor(m, 16));
            m = fmaxf(m, __shfl_xor(m, 32));
            float s = 0.f;
            #pragma unroll
            for (int mi = 0; mi < 4; ++mi)
                #pragma unroll
                for (int r = 0; r < 4; ++r) {
                    float e = __expf(acc_s[mi][ni][r] - m);
                    acc_s[mi][ni][r] = e;
                    s += e;
                }
            s += __shfl_xor(s, 16);
            s += __shfl_xor(s, 32);

            int pcol = p0c + w * 32 + ni * 16 + l15;
            float av = att_s[(((size_t)(n * G_ + g)) * P_) + pcol];  // pre-sigmoided
            float scale = av / s;

            #pragma unroll
            for (int mi = 0; mi < 4; ++mi)
                #pragma unroll
                for (int r = 0; r < 4; ++r) {
                    float wv = acc_s[mi][ni][r] * scale;
                    wsp[mi * 4 + r] += wv;
                    wlds[(mi * 16 + q * 4 + r) * 136 + (w * 32 + ni * 16 + l15)] = (short)f2b(wv);
                }
        }
        __syncthreads();   // wlds visible; xglds long since drained

        // ---- agg MFMA: A = w [64k x 128p], B = xg [128d x 128p] (NT) ----
        #pragma unroll
        for (int pk = 0; pk < 4; ++pk) {
            bf16x8 a2[4], b2[2];
            #pragma unroll
            for (int mi = 0; mi < 4; ++mi)
                a2[mi] = *(const bf16x8*)&wlds[(mi * 16 + l15) * 136 + pk * 32 + q * 8];
            #pragma unroll
            for (int ni = 0; ni < 2; ++ni)
                b2[ni] = *(const bf16x8*)&xglds[(w * 32 + ni * 16 + l15) * 136 + pk * 32 + q * 8];
            #pragma unroll
            for (int mi = 0; mi < 4; ++mi)
                #pragma unroll
                for (int ni = 0; ni < 2; ++ni)
                    acc_a[mi][ni] = __builtin_amdgcn_mfma_f32_16x16x32_bf16(a2[mi], b2[ni], acc_a[mi][ni], 0, 0, 0);
        }
        __syncthreads();   // xglds/wlds reads done before next cc re-stages
    }

    // ---- epilogue: disjoint partials, no atomics ----
    size_t base = (((size_t)(n * G_ + g)) * 2 + ph) * 64;
    #pragma unroll
    for (int mi = 0; mi < 4; ++mi)
        #pragma unroll
        for (int ni = 0; ni < 2; ++ni)
            #pragma unroll
            for (int r = 0; r < 4; ++r) {
                int k = mi * 16 + q * 4 + r;
                int d = w * 32 + ni * 16 + l15;
                agg_part[(base + k) * 128 + d] = acc_a[mi][ni][r];
            }

    #pragma unroll
    for (int j = 0; j < 16; ++j) {
        float v = wsp[j];
        v += __shfl_xor(v, 1);
        v += __shfl_xor(v, 2);
        v += __shfl_xor(v, 4);
        v += __shfl_xor(v, 8);
        if (l15 == 0) {
            int k = (j >> 2) * 16 + q * 4 + (j & 3);
            wsum_part[((((size_t)(n * G_ + g)) * 2 + ph) * 4 + w) * 64 + k] = v;
        }
    }
}

// ---------------------------------------------------------------------------
// K5: vlad[n][k][d] = sum_{g,ph} agg_part - (sum) * centroids
__global__ __launch_bounds__(256) void k5_final(const float* __restrict__ agg_part,
                                                const float* __restrict__ wsum_part,
                                                const float* __restrict__ centroids,
                                                float* __restrict__ out) {
    int idx = blockIdx.x * 256 + threadIdx.x;
    int d = idx & 127;
    int k = (idx >> 7) & 63;
    int n = idx >> 13;
    float ws = 0.f;
    #pragma unroll
    for (int g = 0; g < 8; ++g)
        #pragma unroll
        for (int ph = 0; ph < 2; ++ph)
            #pragma unroll
            for (int w2 = 0; w2 < 4; ++w2)
                ws += wsum_part[((((size_t)(n * G_ + g)) * 2 + ph) * 4 + w2) * 64 + k];
    float agg = 0.f;
    #pragma unroll
    for (int g = 0; g < 8; ++g)
        #pragma unroll
        for (int ph = 0; ph < 2; ++ph)
            agg += agg_part[(((((size_t)(n * G_ + g)) * 2 + ph) * 64) + k) * 128 + d];
    out[idx] = agg - ws * centroids[k * 128 + d];
}

// ---------------------------------------------------------------------------
extern "C" void kernel_launch(void* const* d_in, const int* in_sizes, int n_in,
                              void* d_out, int out_size, void* d_ws, size_t ws_size,
                              hipStream_t stream) {
    const float* x         = (const float*)d_in[0];
    const float* W1        = (const float*)d_in[1];
    const float* W2        = (const float*)d_in[2];
    const float* Wc        = (const float*)d_in[3];
    const float* centroids = (const float*)d_in[4];
    float* out = (float*)d_out;

    // Workspace layout (total 120,324,096 B == proven footprint):
    //   W1b      [E*C]        bf16   1,048,576 B @ 0
    //   Vb       [G*K*C]      bf16     524,288 B @ 1,048,576
    //   xhat_t   [N*P*C]      bf16  33,554,432 B @ 1,572,864
    //   xe       [N*E*P]      bf16  67,108,864 B @ 35,127,296
    //   att_s    [N*G*P]      f32    1,048,576 B @ 102,236,160
    //   att_part [N*16*G*P]   f32   16,777,216 B @ 103,284,736 (dead after k3b;
    //   agg_part [N*G*2*K*D]  f32   16,777,216 B @ 103,284,736  aliases att_part)
    //   wsum_part[N*G*2*4*K]  f32      262,144 B @ 120,061,952
    char* ws = (char*)d_ws;
    unsigned short* W1b      = (unsigned short*)(ws + 0);
    unsigned short* Vb       = (unsigned short*)(ws + 1048576);
    unsigned short* xhat_t   = (unsigned short*)(ws + 1572864);
    unsigned short* xe       = (unsigned short*)(ws + 35127296);
    float*          att_s    = (float*)(ws + 102236160);
    float*          att_part = (float*)(ws + 103284736);
    float*          agg_part = (float*)(ws + 103284736);   // alias: att_part dead before K4
    float*          wsum_part= (float*)(ws + 120061952);

    hipLaunchKernelGGL(k0_prep,        dim3(1024), dim3(256), 0, stream, W1, Wc, W1b, Vb);
    hipLaunchKernelGGL(k1_norm_transpose, dim3(16, 32), dim3(256), 0, stream, x, xhat_t);
    hipLaunchKernelGGL(k2_gemm_xe,     dim3(64, 32), dim3(256), 0, stream, W1b, xhat_t, xe);
    hipLaunchKernelGGL(k3a_att_part,   dim3(16, 32), dim3(256), 0, stream, xe, W2, att_part);
    hipLaunchKernelGGL(k3b_att_reduce, dim3(1024), dim3(256), 0, stream, att_part, att_s);
    hipLaunchKernelGGL(k4_assign_agg,  dim3(16, 32), dim3(256), 0, stream, Vb, xhat_t, xe,
                       att_s, agg_part, wsum_part);
    hipLaunchKernelGGL(k5_final,       dim3(1024), dim3(256), 0, stream,
                       agg_part, wsum_part, centroids, out);
}